// Round 12
// baseline (178.285 us; speedup 1.0000x reference)
//
#include <hip/hip_runtime.h>
#include <math.h>

#define PROJ 8192
#define CDIM 512
#define HWPOS 196
#define NBATCH 32
#define NSLAB 7             // K padded 196 -> 224 = 7 slabs of 32
#define NSEG 16             // 4 diag + 6 pairs x {fwd, mirror}; 16384 entries each

typedef __attribute__((ext_vector_type(8))) short   short8;
typedef __attribute__((ext_vector_type(4))) float   f32x4;

__device__ __forceinline__ unsigned short f2bf(float f) {
    unsigned u = __float_as_uint(f);
    u += 0x7fff + ((u >> 16) & 1);          // round-to-nearest-even
    return (unsigned short)(u >> 16);
}
__device__ __forceinline__ float bf2f(unsigned short h) {
    return __uint_as_float(((unsigned)h) << 16);
}

// Native LDS atomics (r9/r10-verified). Generic-pointer LDS atomicAdd takes
// the ~2800 cy/wave safe path; ds-native is ~235 cy/wave.
__device__ __forceinline__ void lds_uadd(unsigned* p, unsigned v) {
    __attribute__((address_space(3))) unsigned* lp =
        (__attribute__((address_space(3))) unsigned*)p;
    asm volatile("ds_add_u32 %0, %1" : : "v"(lp), "v"(v) : "memory");
}
__device__ __forceinline__ unsigned lds_uadd_rtn(unsigned* p, unsigned v) {
    __attribute__((address_space(3))) unsigned* lp =
        (__attribute__((address_space(3))) unsigned*)p;
    unsigned r;
    asm volatile("ds_add_rtn_u32 %0, %1, %2\n\ts_waitcnt lgkmcnt(0)"
                 : "=v"(r) : "v"(lp), "v"(v) : "memory");
    return r;
}

// Segment decode (r4..r10-verified packs). seg 0..3: diag (t,t) fwd; 4..9:
// pairs (0,1)(0,2)(0,3)(1,2)(1,3)(2,3) fwd; 10..15: same pairs, mirror.
#define BI_PACK 0x2110002110003210ULL
#define BJ_PACK 0x3323213323213210ULL

// Entry e in [0,16384): r=e>>7, c=e&127 of tile (bi,bj). (r7..r10-verbatim)
__device__ __forceinline__ void seg_entry(int seg, int e,
    const int* __restrict__ h1, const float* __restrict__ s1,
    const int* __restrict__ h2, const float* __restrict__ s2,
    int& bin, int& sg)
{
    const int bi = (int)((BI_PACK >> (seg * 4)) & 15);
    const int bj = (int)((BJ_PACK >> (seg * 4)) & 15);
    const int r = e >> 7, c = e & 127;
    int gi, gj;
    if (seg < 10) { gi = bi * 128 + r; gj = bj * 128 + c; }
    else          { gi = bj * 128 + c; gj = bi * 128 + r; }
    bin = (h1[gi] + h2[gj]) & (PROJ - 1);
    sg  = (int)((__float_as_uint(s1[gi]) ^ __float_as_uint(s2[gj])) >> 31); // s=+-1
}

// ---------------------------------------------------------------------------
// Kernel 1: prep — fp32 x -> bf16 hi/lo, fragment order. (r0 verbatim)
// Launched FIRST: its 14.7 MB XThi/XTlo writeback drains during the
// extract+build launches (r9->r10 A/B: gram is 51.5us behind a quiet
// window, 71.8us directly behind this writeback).
// ---------------------------------------------------------------------------
__global__ __launch_bounds__(256) void prep_kernel(
    const float* __restrict__ x,
    unsigned short* __restrict__ XThi, unsigned short* __restrict__ XTlo)
{
    const int ks  = blockIdx.x;
    const int bat = blockIdx.y;
    const int tid = threadIdx.x;
    __shared__ float xt[32][513];            // +1 pad breaks bank conflicts

    const float* xb = x + (size_t)bat * HWPOS * CDIM;
    const int k0 = ks * 32;
#pragma unroll
    for (int i = 0; i < 16; ++i) {
        const int idx = i * 1024 + tid * 4;
        const int kr  = idx >> 9;
        const int c   = idx & 511;
        float4 v = make_float4(0.f, 0.f, 0.f, 0.f);
        if (k0 + kr < HWPOS) v = *(const float4*)(xb + (size_t)(k0 + kr) * CDIM + c);
        xt[kr][c+0] = v.x; xt[kr][c+1] = v.y; xt[kr][c+2] = v.z; xt[kr][c+3] = v.w;
    }
    __syncthreads();

    unsigned short* ohi = XThi + ((size_t)bat * NSLAB + ks) * 16384;
    unsigned short* olo = XTlo + ((size_t)bat * NSLAB + ks) * 16384;
#pragma unroll
    for (int i = 0; i < 8; ++i) {
        const int ch   = i * 256 + tid;      // chunk 0..2047, memory order
        const int c16  = ch & 15;
        const int quad = (ch >> 4) & 3;
        const int cgrp = ch >> 6;
        const int c    = cgrp * 16 + c16;
        short8 vh, vl;
#pragma unroll
        for (int j = 0; j < 8; ++j) {
            float f = xt[quad * 8 + j][c];
            unsigned short h = f2bf(f);
            vh[j] = (short)h;
            vl[j] = (short)f2bf(f - bf2f(h));
        }
        *(short8*)(ohi + ch * 8) = vh;
        *(short8*)(olo + ch * 8) = vl;
    }
}

// ---------------------------------------------------------------------------
// Kernel 2: extract (h, s) from dense sketch matrices (r9 body) + zero norm
// + zero this block's 16 KB chunk of pbins (r10-verified branch; gram's
// gather writes every touched bin exactly once, untouched bins keep zeros).
// Grid (512, 2) -> bid = x*2+y covers 1024 chunks of 4096 floats.
// ---------------------------------------------------------------------------
__global__ __launch_bounds__(256) void extract_kernel(
    const float* __restrict__ M1, const float* __restrict__ M2,
    int* __restrict__ h1, float* __restrict__ s1,
    int* __restrict__ h2, float* __restrict__ s2,
    float* __restrict__ norm, float* __restrict__ pbins)
{
    const int row = blockIdx.x;
    const float* M = blockIdx.y ? M2 : M1;
    int*   h = blockIdx.y ? h2 : h1;
    float* s = blockIdx.y ? s2 : s1;
    const float* mrow = M + (size_t)row * PROJ;

    if (blockIdx.x == 0 && blockIdx.y == 0 && threadIdx.x < NBATCH)
        norm[threadIdx.x] = 0.0f;

    for (int i = threadIdx.x * 4; i < PROJ; i += 256 * 4) {
        float4 v = *(const float4*)(mrow + i);
        if (v.x != 0.0f) { h[row] = i + 0; s[row] = v.x; }
        if (v.y != 0.0f) { h[row] = i + 1; s[row] = v.y; }
        if (v.z != 0.0f) { h[row] = i + 2; s[row] = v.z; }
        if (v.w != 0.0f) { h[row] = i + 3; s[row] = v.w; }
    }

    // zero one 4096-float chunk of pbins (1024 blocks x 16 KB = 16.7 MB)
    const int bid = blockIdx.x * 2 + blockIdx.y;
    float* pz = pbins + (size_t)bid * 4096;
#pragma unroll
    for (int i = 0; i < 4; ++i)
        *(float4*)(pz + i * 1024 + threadIdx.x * 4) = make_float4(0.f, 0.f, 0.f, 0.f);
}

// ---------------------------------------------------------------------------
// Kernel 3: build — bin-sorted u32 CSR per segment (r9/r10-verified body:
// direct __shared__ typed arrays + native ds atomics). 16 blocks.
// ---------------------------------------------------------------------------
__global__ __launch_bounds__(256) void build_kernel(
    const int* __restrict__ h1, const float* __restrict__ s1,
    const int* __restrict__ h2, const float* __restrict__ s2,
    unsigned* __restrict__ csr)
{
    __shared__ unsigned cnt[PROJ];            // 32 KB
    __shared__ unsigned sc[256];
    const int tid = threadIdx.x;
    const int seg = blockIdx.x;

    for (int i = tid; i < PROJ; i += 256) cnt[i] = 0u;
    __syncthreads();
#pragma unroll 8
    for (int k = 0; k < 64; ++k) {                // pass 1: histogram
        const int e = k * 256 + tid;
        int bin, sg;
        seg_entry(seg, e, h1, s1, h2, s2, bin, sg);
        lds_uadd(&cnt[bin], 1u);
    }
    __syncthreads();                              // lgkm drain covers ds_adds

    unsigned c[32]; unsigned tot = 0;             // thread owns bins [tid*32,+32)
#pragma unroll
    for (int i = 0; i < 32; ++i) { c[i] = cnt[tid * 32 + i]; tot += c[i]; }
    sc[tid] = tot;
    __syncthreads();
    for (int off = 1; off < 256; off <<= 1) {     // Hillis-Steele inclusive
        unsigned v = (tid >= off) ? sc[tid - off] : 0u;
        __syncthreads();
        sc[tid] += v;
        __syncthreads();
    }
    unsigned base = sc[tid] - tot;                // exclusive prefix
#pragma unroll
    for (int i = 0; i < 32; ++i) { unsigned t = c[i]; cnt[tid * 32 + i] = base; base += t; }
    __syncthreads();

    unsigned* cs = csr + (size_t)seg * 16384;
#pragma unroll 8
    for (int k = 0; k < 64; ++k) {                // pass 2: place
        const int e = k * 256 + tid;
        int bin, sg;
        seg_entry(seg, e, h1, s1, h2, s2, bin, sg);
        const unsigned pos = lds_uadd_rtn(&cnt[bin], 1u);
        cs[pos] = ((unsigned)bin << 15) | ((unsigned)sg << 14) | (unsigned)e;
    }
}

// ---------------------------------------------------------------------------
// Kernel 4: Gram — r10 VERBATIM (passed, 51.5 us): double-buffered staging +
// MFMA + tile-store + position-regular segmented gather to pre-zeroed
// global pages (interior runs plain store, boundary runs atomic).
// ---------------------------------------------------------------------------
__global__ __launch_bounds__(256) void gramgather_kernel(
    const unsigned short* __restrict__ XThi, const unsigned short* __restrict__ XTlo,
    const unsigned* __restrict__ csr, float* __restrict__ pbins)
{
    const int id  = blockIdx.x;                   // 0..511
    const int sub = id >> 3;                      // 0..63
    const int tp  = sub & 15;                     // segment 0..15
    const int bat = (id & 7) + 8 * (sub >> 4);    // XCD swizzle
    const int bi = (int)((BI_PACK >> (tp * 4)) & 15);
    const int bj = (int)((BJ_PACK >> (tp * 4)) & 15);

    const int tid  = threadIdx.x;
    const int w    = tid >> 6;
    const int lane = tid & 63;
    const int rowq = w >> 1, colq = w & 1;

    __shared__ __align__(16) unsigned short Sbuf[2][4][4096]; // 64 KB dbuf -> tile

    const int tile = (w < 2) ? bi : bj;
    const unsigned short* srcbase = ((w & 1) ? XTlo : XThi)
                                  + (size_t)bat * NSLAB * 16384 + (size_t)tile * 4096;

    // issue async prefetch of slab 0 (r4 verbatim)
    {
        const unsigned short* src = srcbase;
        unsigned short* dst = &Sbuf[0][w][0];
#pragma unroll
        for (int i = 0; i < 8; ++i)
            __builtin_amdgcn_global_load_lds(
                (const __attribute__((address_space(1))) void*)(src + i * 512 + lane * 8),
                (__attribute__((address_space(3))) void*)(dst + i * 512), 16, 0, 0);
    }

    float* page = pbins + ((size_t)bat * NSEG + tp) * PROJ;

    f32x4 acc[16];
#pragma unroll
    for (int i = 0; i < 16; ++i) { acc[i][0]=0.f; acc[i][1]=0.f; acc[i][2]=0.f; acc[i][3]=0.f; }

    for (int ks = 0; ks < NSLAB; ++ks) {
        __syncthreads();                 // drains vmcnt -> slab ks resident
        const int buf = ks & 1;

        if (ks + 1 < NSLAB) {            // prefetch next slab into other buffer
            const unsigned short* src = srcbase + (size_t)(ks + 1) * 16384;
            unsigned short* dst = &Sbuf[buf ^ 1][w][0];
#pragma unroll
            for (int i = 0; i < 8; ++i)
                __builtin_amdgcn_global_load_lds(
                    (const __attribute__((address_space(1))) void*)(src + i * 512 + lane * 8),
                    (__attribute__((address_space(3))) void*)(dst + i * 512), 16, 0, 0);
        }

        short8 ah[4], al[4], bh4[4], bl[4];
#pragma unroll
        for (int t = 0; t < 4; ++t) {
            ah[t]  = *(const short8*)&Sbuf[buf][0][(rowq * 4 + t) * 512 + lane * 8];
            al[t]  = *(const short8*)&Sbuf[buf][1][(rowq * 4 + t) * 512 + lane * 8];
            bh4[t] = *(const short8*)&Sbuf[buf][2][(colq * 4 + t) * 512 + lane * 8];
            bl[t]  = *(const short8*)&Sbuf[buf][3][(colq * 4 + t) * 512 + lane * 8];
        }
#pragma unroll
        for (int mt = 0; mt < 4; ++mt)
#pragma unroll
            for (int nt = 0; nt < 4; ++nt) {
                const int idx = mt * 4 + nt;
                acc[idx] = __builtin_amdgcn_mfma_f32_16x16x32_bf16(ah[mt], bh4[nt], acc[idx], 0, 0, 0);
                acc[idx] = __builtin_amdgcn_mfma_f32_16x16x32_bf16(ah[mt], bl[nt],  acc[idx], 0, 0, 0);
                acc[idx] = __builtin_amdgcn_mfma_f32_16x16x32_bf16(al[mt], bh4[nt], acc[idx], 0, 0, 0);
            }
    }

    __syncthreads();                     // all waves done with Sbuf -> reuse as tile
    float* tileL = (float*)Sbuf;         // 16384 f32 = 64 KB exactly
    const int quad = lane >> 4;
#pragma unroll
    for (int mt = 0; mt < 4; ++mt)
#pragma unroll
        for (int reg = 0; reg < 4; ++reg) {
            const int rl = rowq * 64 + mt * 16 + quad * 4 + reg;
#pragma unroll
            for (int nt = 0; nt < 4; ++nt) {
                const int cl = colq * 64 + nt * 16 + (lane & 15);
                tileL[rl * 128 + cl] = acc[mt * 4 + nt][reg];
            }
        }
    __syncthreads();                     // tile visible to all waves

    // ---- position-regular segmented gather (r8/r10-verbatim) ----
    const uint4* ce = (const uint4*)(csr + (size_t)tp * 16384 + (size_t)tid * 64);
    uint4 E[16];
#pragma unroll
    for (int i = 0; i < 16; ++i) E[i] = ce[i];

    float a = 0.f;
    unsigned cur = E[0].x >> 15;
    bool first = true;
#pragma unroll
    for (int i = 0; i < 16; ++i) {
#pragma unroll
        for (int j = 0; j < 4; ++j) {
            const unsigned ent = (j == 0) ? E[i].x : (j == 1) ? E[i].y
                               : (j == 2) ? E[i].z : E[i].w;
            const unsigned b = ent >> 15;
            float v = tileL[ent & 0x3FFF];
            v = (ent & 0x4000u) ? -v : v;
            if (b != cur) {
                if (first) { unsafeAtomicAdd(&page[cur], a); first = false; }
                else       { page[cur] = a; }
                cur = b; a = v;
            } else {
                a += v;
            }
        }
    }
    unsafeAtomicAdd(&page[cur], a);      // final run always atomic
}

// ---------------------------------------------------------------------------
// Kernel 5: reduce NSEG partials per bin, signed sqrt, emit unnormalized y,
// accumulate per-batch sum |v| (== sum y^2). Grid (8, 32). (r9 verbatim)
// ---------------------------------------------------------------------------
__global__ __launch_bounds__(256) void reduce_kernel(
    const float* __restrict__ pbins, float* __restrict__ out,
    float* __restrict__ norm)
{
    const int chunk = blockIdx.x;
    const int bat   = blockIdx.y;
    const int tid   = threadIdx.x;
    const int base  = chunk * 1024 + tid * 4;

    const float* pb = pbins + (size_t)bat * NSEG * PROJ;
    float4 v = make_float4(0.f, 0.f, 0.f, 0.f);
#pragma unroll
    for (int t = 0; t < NSEG; ++t) {
        float4 p = *(const float4*)(pb + (size_t)t * PROJ + base);
        v.x += p.x; v.y += p.y; v.z += p.z; v.w += p.w;
    }

    float4 sv;
    sv.x = (v.x >= 0.f) ? sqrtf(v.x) : -sqrtf(-v.x);
    sv.y = (v.y >= 0.f) ? sqrtf(v.y) : -sqrtf(-v.y);
    sv.z = (v.z >= 0.f) ? sqrtf(v.z) : -sqrtf(-v.z);
    sv.w = (v.w >= 0.f) ? sqrtf(v.w) : -sqrtf(-v.w);
    *(float4*)(out + (size_t)bat * PROJ + base) = sv;

    float local = fabsf(v.x) + fabsf(v.y) + fabsf(v.z) + fabsf(v.w);
#pragma unroll
    for (int off = 32; off > 0; off >>= 1) local += __shfl_down(local, off, 64);

    __shared__ float wred[4];
    if ((tid & 63) == 0) wred[tid >> 6] = local;
    __syncthreads();
    if (tid == 0)
        unsafeAtomicAdd(&norm[bat], wred[0] + wred[1] + wred[2] + wred[3]);
}

// ---------------------------------------------------------------------------
// Kernel 6: scale by rsqrt(norm). Grid (8, 32). (r9 verbatim)
// ---------------------------------------------------------------------------
__global__ __launch_bounds__(256) void normalize_kernel(
    float* __restrict__ out, const float* __restrict__ norm)
{
    const int bat = blockIdx.y;
    const int idx = blockIdx.x * 1024 + threadIdx.x * 4;
    const float inv = rsqrtf(fmaxf(norm[bat], 1e-10f));
    float4* p = (float4*)(out + (size_t)bat * PROJ + idx);
    float4 v = *p;
    v.x *= inv; v.y *= inv; v.z *= inv; v.w *= inv;
    *p = v;
}

// ---------------------------------------------------------------------------
extern "C" void kernel_launch(void* const* d_in, const int* in_sizes, int n_in,
                              void* d_out, int out_size, void* d_ws, size_t ws_size,
                              hipStream_t stream)
{
    const float* x  = (const float*)d_in[0];   // [32,14,14,512]
    const float* M1 = (const float*)d_in[1];   // [512,8192]
    const float* M2 = (const float*)d_in[2];   // [512,8192]
    float* out = (float*)d_out;                // [32,8192]

    char* ws = (char*)d_ws;
    int*            h1    = (int*)   (ws + 0);
    float*          s1    = (float*) (ws + 2048);
    int*            h2    = (int*)   (ws + 4096);
    float*          s2    = (float*) (ws + 6144);
    float*          norm  = (float*) (ws + 8192);
    unsigned*       csr   = (unsigned*)(ws + 16384);            // 1,048,576 B
    unsigned short* XThi  = (unsigned short*)(ws + 1064960);    // 7,340,032 B
    unsigned short* XTlo  = (unsigned short*)(ws + 8404992);    // 7,340,032 B
    float*          pbins = (float*) (ws + 15745024);           // 16,777,216 B
    // total ws use 32,522,240 B = 31.02 MiB (== r7..r11 proven footprint)

    prep_kernel<<<dim3(NSLAB, NBATCH), 256, 0, stream>>>(x, XThi, XTlo);
    extract_kernel<<<dim3(512, 2), 256, 0, stream>>>(M1, M2, h1, s1, h2, s2, norm, pbins);
    build_kernel<<<NSEG, 256, 0, stream>>>(h1, s1, h2, s2, csr);
    gramgather_kernel<<<NSEG * NBATCH, 256, 0, stream>>>(XThi, XTlo, csr, pbins);
    reduce_kernel<<<dim3(8, NBATCH), 256, 0, stream>>>(pbins, out, norm);
    normalize_kernel<<<dim3(8, NBATCH), 256, 0, stream>>>(out, norm);
}

// Round 13
// 163.262 us; speedup vs baseline: 1.0920x; 1.0920x over previous
//
#include <hip/hip_runtime.h>
#include <math.h>

#define PROJ 8192
#define CDIM 512
#define HWPOS 196
#define NBATCH 32
#define NSLAB 7             // K padded 196 -> 224 = 7 slabs of 32
#define NSEG 16             // 4 diag + 6 pairs x {fwd, mirror}; 16384 entries each

typedef __attribute__((ext_vector_type(8))) short   short8;
typedef __attribute__((ext_vector_type(4))) float   f32x4;

__device__ __forceinline__ unsigned short f2bf(float f) {
    unsigned u = __float_as_uint(f);
    u += 0x7fff + ((u >> 16) & 1);          // round-to-nearest-even
    return (unsigned short)(u >> 16);
}
__device__ __forceinline__ float bf2f(unsigned short h) {
    return __uint_as_float(((unsigned)h) << 16);
}

// Native LDS atomics (r9..r12-verified). Generic-pointer LDS atomicAdd takes
// the ~2800 cy/wave safe path; ds-native is ~235 cy/wave.
__device__ __forceinline__ void lds_uadd(unsigned* p, unsigned v) {
    __attribute__((address_space(3))) unsigned* lp =
        (__attribute__((address_space(3))) unsigned*)p;
    asm volatile("ds_add_u32 %0, %1" : : "v"(lp), "v"(v) : "memory");
}
__device__ __forceinline__ unsigned lds_uadd_rtn(unsigned* p, unsigned v) {
    __attribute__((address_space(3))) unsigned* lp =
        (__attribute__((address_space(3))) unsigned*)p;
    unsigned r;
    asm volatile("ds_add_rtn_u32 %0, %1, %2\n\ts_waitcnt lgkmcnt(0)"
                 : "=v"(r) : "v"(lp), "v"(v) : "memory");
    return r;
}

// Segment decode (r4..r12-verified packs). seg 0..3: diag (t,t) fwd; 4..9:
// pairs (0,1)(0,2)(0,3)(1,2)(1,3)(2,3) fwd; 10..15: same pairs, mirror.
#define BI_PACK 0x2110002110003210ULL
#define BJ_PACK 0x3323213323213210ULL

// Entry e in [0,16384): r=e>>7, c=e&127 of tile (bi,bj). (r7..r12-verbatim)
__device__ __forceinline__ void seg_entry(int seg, int e,
    const int* __restrict__ h1, const float* __restrict__ s1,
    const int* __restrict__ h2, const float* __restrict__ s2,
    int& bin, int& sg)
{
    const int bi = (int)((BI_PACK >> (seg * 4)) & 15);
    const int bj = (int)((BJ_PACK >> (seg * 4)) & 15);
    const int r = e >> 7, c = e & 127;
    int gi, gj;
    if (seg < 10) { gi = bi * 128 + r; gj = bj * 128 + c; }
    else          { gi = bj * 128 + c; gj = bi * 128 + r; }
    bin = (h1[gi] + h2[gj]) & (PROJ - 1);
    sg  = (int)((__float_as_uint(s1[gi]) ^ __float_as_uint(s2[gj])) >> 31); // s=+-1
}

// ---------------------------------------------------------------------------
// Kernel 1: extract (h,s) + zero norm + zero pbins. (r12 verbatim — no
// __shared__, so full occupancy for the 1024 light blocks; the r10 lesson:
// fusing light blocks into a heavy-LDS kernel halves their occupancy.)
// ---------------------------------------------------------------------------
__global__ __launch_bounds__(256) void extract_kernel(
    const float* __restrict__ M1, const float* __restrict__ M2,
    int* __restrict__ h1, float* __restrict__ s1,
    int* __restrict__ h2, float* __restrict__ s2,
    float* __restrict__ norm, float* __restrict__ pbins)
{
    const int row = blockIdx.x;
    const float* M = blockIdx.y ? M2 : M1;
    int*   h = blockIdx.y ? h2 : h1;
    float* s = blockIdx.y ? s2 : s1;
    const float* mrow = M + (size_t)row * PROJ;

    if (blockIdx.x == 0 && blockIdx.y == 0 && threadIdx.x < NBATCH)
        norm[threadIdx.x] = 0.0f;

    for (int i = threadIdx.x * 4; i < PROJ; i += 256 * 4) {
        float4 v = *(const float4*)(mrow + i);
        if (v.x != 0.0f) { h[row] = i + 0; s[row] = v.x; }
        if (v.y != 0.0f) { h[row] = i + 1; s[row] = v.y; }
        if (v.z != 0.0f) { h[row] = i + 2; s[row] = v.z; }
        if (v.w != 0.0f) { h[row] = i + 3; s[row] = v.w; }
    }

    // zero one 4096-float chunk of pbins (1024 blocks x 16 KB = 16.7 MB)
    const int bid = blockIdx.x * 2 + blockIdx.y;
    float* pz = pbins + (size_t)bid * 4096;
#pragma unroll
    for (int i = 0; i < 4; ++i)
        *(float4*)(pz + i * 1024 + threadIdx.x * 4) = make_float4(0.f, 0.f, 0.f, 0.f);
}

// ---------------------------------------------------------------------------
// Kernel 2: combo — blocks 0..223 prep (r0 body); blocks 224..239 build the
// bin-sorted u32 CSR, one segment each (r9-verified; build runs CONCURRENT
// with prep — the 16 build blocks don't care about the 65.7 KB LDS max).
// ---------------------------------------------------------------------------
__global__ __launch_bounds__(256) void combo_kernel(
    const float* __restrict__ x,
    unsigned short* __restrict__ XThi, unsigned short* __restrict__ XTlo,
    const int* __restrict__ h1, const float* __restrict__ s1,
    const int* __restrict__ h2, const float* __restrict__ s2,
    unsigned* __restrict__ csr)
{
    __shared__ float    xt[32][513];          // prep transpose buffer
    __shared__ unsigned cnt[PROJ];            // build histogram/bases
    __shared__ unsigned sc[256];
    const int tid = threadIdx.x;

    if (blockIdx.x < 224) {
        // ---- prep: split fp32 x into bf16 hi/lo, fragment order (r0) ----
        const int ks = blockIdx.x % NSLAB;
        const int bt = blockIdx.x / NSLAB;        // 0..31
        const float* xb = x + (size_t)bt * HWPOS * CDIM;
        const int k0 = ks * 32;
#pragma unroll
        for (int i = 0; i < 16; ++i) {
            const int idx = i * 1024 + tid * 4;
            const int kr  = idx >> 9;
            const int c   = idx & 511;
            float4 v = make_float4(0.f, 0.f, 0.f, 0.f);
            if (k0 + kr < HWPOS) v = *(const float4*)(xb + (size_t)(k0 + kr) * CDIM + c);
            xt[kr][c+0] = v.x; xt[kr][c+1] = v.y; xt[kr][c+2] = v.z; xt[kr][c+3] = v.w;
        }
        __syncthreads();

        unsigned short* ohi = XThi + ((size_t)bt * NSLAB + ks) * 16384;
        unsigned short* olo = XTlo + ((size_t)bt * NSLAB + ks) * 16384;
#pragma unroll
        for (int i = 0; i < 8; ++i) {
            const int ch   = i * 256 + tid;
            const int c16  = ch & 15;
            const int quad = (ch >> 4) & 3;
            const int cgrp = ch >> 6;
            const int c    = cgrp * 16 + c16;
            short8 vh, vl;
#pragma unroll
            for (int j = 0; j < 8; ++j) {
                float f = xt[quad * 8 + j][c];
                unsigned short h = f2bf(f);
                vh[j] = (short)h;
                vl[j] = (short)f2bf(f - bf2f(h));
            }
            *(short8*)(ohi + ch * 8) = vh;
            *(short8*)(olo + ch * 8) = vl;
        }
    } else {
        // ---- buildcsr for segment seg (native ds atomics, r9-verified) ----
        const int seg = blockIdx.x - 224;

        for (int i = tid; i < PROJ; i += 256) cnt[i] = 0u;
        __syncthreads();
#pragma unroll 8
        for (int k = 0; k < 64; ++k) {                // pass 1: histogram
            const int e = k * 256 + tid;
            int bin, sg;
            seg_entry(seg, e, h1, s1, h2, s2, bin, sg);
            lds_uadd(&cnt[bin], 1u);
        }
        __syncthreads();                              // lgkm drain covers ds_adds

        unsigned c[32]; unsigned tot = 0;             // thread owns bins [tid*32,+32)
#pragma unroll
        for (int i = 0; i < 32; ++i) { c[i] = cnt[tid * 32 + i]; tot += c[i]; }
        sc[tid] = tot;
        __syncthreads();
        for (int off = 1; off < 256; off <<= 1) {     // Hillis-Steele inclusive
            unsigned v = (tid >= off) ? sc[tid - off] : 0u;
            __syncthreads();
            sc[tid] += v;
            __syncthreads();
        }
        unsigned base = sc[tid] - tot;                // exclusive prefix
#pragma unroll
        for (int i = 0; i < 32; ++i) { unsigned t = c[i]; cnt[tid * 32 + i] = base; base += t; }
        __syncthreads();

        unsigned* cs = csr + (size_t)seg * 16384;
#pragma unroll 8
        for (int k = 0; k < 64; ++k) {                // pass 2: place
            const int e = k * 256 + tid;
            int bin, sg;
            seg_entry(seg, e, h1, s1, h2, s2, bin, sg);
            const unsigned pos = lds_uadd_rtn(&cnt[bin], 1u);
            cs[pos] = ((unsigned)bin << 15) | ((unsigned)sg << 14) | (unsigned)e;
        }
    }
}

// ---------------------------------------------------------------------------
// Kernel 3: Gram — r10/r12 VERBATIM (passed, 51.5/51.9 us): double-buffered
// staging + MFMA + tile-store + position-regular segmented gather to
// pre-zeroed global pages (interior runs plain store, boundary runs atomic).
// ---------------------------------------------------------------------------
__global__ __launch_bounds__(256) void gramgather_kernel(
    const unsigned short* __restrict__ XThi, const unsigned short* __restrict__ XTlo,
    const unsigned* __restrict__ csr, float* __restrict__ pbins)
{
    const int id  = blockIdx.x;                   // 0..511
    const int sub = id >> 3;                      // 0..63
    const int tp  = sub & 15;                     // segment 0..15
    const int bat = (id & 7) + 8 * (sub >> 4);    // XCD swizzle
    const int bi = (int)((BI_PACK >> (tp * 4)) & 15);
    const int bj = (int)((BJ_PACK >> (tp * 4)) & 15);

    const int tid  = threadIdx.x;
    const int w    = tid >> 6;
    const int lane = tid & 63;
    const int rowq = w >> 1, colq = w & 1;

    __shared__ __align__(16) unsigned short Sbuf[2][4][4096]; // 64 KB dbuf -> tile

    const int tile = (w < 2) ? bi : bj;
    const unsigned short* srcbase = ((w & 1) ? XTlo : XThi)
                                  + (size_t)bat * NSLAB * 16384 + (size_t)tile * 4096;

    // issue async prefetch of slab 0 (r4 verbatim)
    {
        const unsigned short* src = srcbase;
        unsigned short* dst = &Sbuf[0][w][0];
#pragma unroll
        for (int i = 0; i < 8; ++i)
            __builtin_amdgcn_global_load_lds(
                (const __attribute__((address_space(1))) void*)(src + i * 512 + lane * 8),
                (__attribute__((address_space(3))) void*)(dst + i * 512), 16, 0, 0);
    }

    float* page = pbins + ((size_t)bat * NSEG + tp) * PROJ;

    f32x4 acc[16];
#pragma unroll
    for (int i = 0; i < 16; ++i) { acc[i][0]=0.f; acc[i][1]=0.f; acc[i][2]=0.f; acc[i][3]=0.f; }

    for (int ks = 0; ks < NSLAB; ++ks) {
        __syncthreads();                 // drains vmcnt -> slab ks resident
        const int buf = ks & 1;

        if (ks + 1 < NSLAB) {            // prefetch next slab into other buffer
            const unsigned short* src = srcbase + (size_t)(ks + 1) * 16384;
            unsigned short* dst = &Sbuf[buf ^ 1][w][0];
#pragma unroll
            for (int i = 0; i < 8; ++i)
                __builtin_amdgcn_global_load_lds(
                    (const __attribute__((address_space(1))) void*)(src + i * 512 + lane * 8),
                    (__attribute__((address_space(3))) void*)(dst + i * 512), 16, 0, 0);
        }

        short8 ah[4], al[4], bh4[4], bl[4];
#pragma unroll
        for (int t = 0; t < 4; ++t) {
            ah[t]  = *(const short8*)&Sbuf[buf][0][(rowq * 4 + t) * 512 + lane * 8];
            al[t]  = *(const short8*)&Sbuf[buf][1][(rowq * 4 + t) * 512 + lane * 8];
            bh4[t] = *(const short8*)&Sbuf[buf][2][(colq * 4 + t) * 512 + lane * 8];
            bl[t]  = *(const short8*)&Sbuf[buf][3][(colq * 4 + t) * 512 + lane * 8];
        }
#pragma unroll
        for (int mt = 0; mt < 4; ++mt)
#pragma unroll
            for (int nt = 0; nt < 4; ++nt) {
                const int idx = mt * 4 + nt;
                acc[idx] = __builtin_amdgcn_mfma_f32_16x16x32_bf16(ah[mt], bh4[nt], acc[idx], 0, 0, 0);
                acc[idx] = __builtin_amdgcn_mfma_f32_16x16x32_bf16(ah[mt], bl[nt],  acc[idx], 0, 0, 0);
                acc[idx] = __builtin_amdgcn_mfma_f32_16x16x32_bf16(al[mt], bh4[nt], acc[idx], 0, 0, 0);
            }
    }

    __syncthreads();                     // all waves done with Sbuf -> reuse as tile
    float* tileL = (float*)Sbuf;         // 16384 f32 = 64 KB exactly
    const int quad = lane >> 4;
#pragma unroll
    for (int mt = 0; mt < 4; ++mt)
#pragma unroll
        for (int reg = 0; reg < 4; ++reg) {
            const int rl = rowq * 64 + mt * 16 + quad * 4 + reg;
#pragma unroll
            for (int nt = 0; nt < 4; ++nt) {
                const int cl = colq * 64 + nt * 16 + (lane & 15);
                tileL[rl * 128 + cl] = acc[mt * 4 + nt][reg];
            }
        }
    __syncthreads();                     // tile visible to all waves

    // ---- position-regular segmented gather (r8/r10-verbatim) ----
    const uint4* ce = (const uint4*)(csr + (size_t)tp * 16384 + (size_t)tid * 64);
    uint4 E[16];
#pragma unroll
    for (int i = 0; i < 16; ++i) E[i] = ce[i];

    float a = 0.f;
    unsigned cur = E[0].x >> 15;
    bool first = true;
#pragma unroll
    for (int i = 0; i < 16; ++i) {
#pragma unroll
        for (int j = 0; j < 4; ++j) {
            const unsigned ent = (j == 0) ? E[i].x : (j == 1) ? E[i].y
                               : (j == 2) ? E[i].z : E[i].w;
            const unsigned b = ent >> 15;
            float v = tileL[ent & 0x3FFF];
            v = (ent & 0x4000u) ? -v : v;
            if (b != cur) {
                if (first) { unsafeAtomicAdd(&page[cur], a); first = false; }
                else       { page[cur] = a; }
                cur = b; a = v;
            } else {
                a += v;
            }
        }
    }
    unsafeAtomicAdd(&page[cur], a);      // final run always atomic
}

// ---------------------------------------------------------------------------
// Kernel 4: reduce NSEG partials per bin, signed sqrt, emit unnormalized y,
// accumulate per-batch sum |v| (== sum y^2). Grid (8, 32). (r9 verbatim)
// ---------------------------------------------------------------------------
__global__ __launch_bounds__(256) void reduce_kernel(
    const float* __restrict__ pbins, float* __restrict__ out,
    float* __restrict__ norm)
{
    const int chunk = blockIdx.x;
    const int bat   = blockIdx.y;
    const int tid   = threadIdx.x;
    const int base  = chunk * 1024 + tid * 4;

    const float* pb = pbins + (size_t)bat * NSEG * PROJ;
    float4 v = make_float4(0.f, 0.f, 0.f, 0.f);
#pragma unroll
    for (int t = 0; t < NSEG; ++t) {
        float4 p = *(const float4*)(pb + (size_t)t * PROJ + base);
        v.x += p.x; v.y += p.y; v.z += p.z; v.w += p.w;
    }

    float4 sv;
    sv.x = (v.x >= 0.f) ? sqrtf(v.x) : -sqrtf(-v.x);
    sv.y = (v.y >= 0.f) ? sqrtf(v.y) : -sqrtf(-v.y);
    sv.z = (v.z >= 0.f) ? sqrtf(v.z) : -sqrtf(-v.z);
    sv.w = (v.w >= 0.f) ? sqrtf(v.w) : -sqrtf(-v.w);
    *(float4*)(out + (size_t)bat * PROJ + base) = sv;

    float local = fabsf(v.x) + fabsf(v.y) + fabsf(v.z) + fabsf(v.w);
#pragma unroll
    for (int off = 32; off > 0; off >>= 1) local += __shfl_down(local, off, 64);

    __shared__ float wred[4];
    if ((tid & 63) == 0) wred[tid >> 6] = local;
    __syncthreads();
    if (tid == 0)
        unsafeAtomicAdd(&norm[bat], wred[0] + wred[1] + wred[2] + wred[3]);
}

// ---------------------------------------------------------------------------
// Kernel 5: scale by rsqrt(norm). Grid (8, 32). (r9 verbatim)
// ---------------------------------------------------------------------------
__global__ __launch_bounds__(256) void normalize_kernel(
    float* __restrict__ out, const float* __restrict__ norm)
{
    const int bat = blockIdx.y;
    const int idx = blockIdx.x * 1024 + threadIdx.x * 4;
    const float inv = rsqrtf(fmaxf(norm[bat], 1e-10f));
    float4* p = (float4*)(out + (size_t)bat * PROJ + idx);
    float4 v = *p;
    v.x *= inv; v.y *= inv; v.z *= inv; v.w *= inv;
    *p = v;
}

// ---------------------------------------------------------------------------
extern "C" void kernel_launch(void* const* d_in, const int* in_sizes, int n_in,
                              void* d_out, int out_size, void* d_ws, size_t ws_size,
                              hipStream_t stream)
{
    const float* x  = (const float*)d_in[0];   // [32,14,14,512]
    const float* M1 = (const float*)d_in[1];   // [512,8192]
    const float* M2 = (const float*)d_in[2];   // [512,8192]
    float* out = (float*)d_out;                // [32,8192]

    char* ws = (char*)d_ws;
    int*            h1    = (int*)   (ws + 0);
    float*          s1    = (float*) (ws + 2048);
    int*            h2    = (int*)   (ws + 4096);
    float*          s2    = (float*) (ws + 6144);
    float*          norm  = (float*) (ws + 8192);
    unsigned*       csr   = (unsigned*)(ws + 16384);            // 1,048,576 B
    unsigned short* XThi  = (unsigned short*)(ws + 1064960);    // 7,340,032 B
    unsigned short* XTlo  = (unsigned short*)(ws + 8404992);    // 7,340,032 B
    float*          pbins = (float*) (ws + 15745024);           // 16,777,216 B
    // total ws use 32,522,240 B = 31.02 MiB (== r7..r12 proven footprint)

    extract_kernel<<<dim3(512, 2), 256, 0, stream>>>(M1, M2, h1, s1, h2, s2, norm, pbins);
    combo_kernel<<<240, 256, 0, stream>>>(x, XThi, XTlo, h1, s1, h2, s2, csr);
    gramgather_kernel<<<NSEG * NBATCH, 256, 0, stream>>>(XThi, XTlo, csr, pbins);
    reduce_kernel<<<dim3(8, NBATCH), 256, 0, stream>>>(pbins, out, norm);
    normalize_kernel<<<dim3(8, NBATCH), 256, 0, stream>>>(out, norm);
}